// Round 4
// baseline (277.209 us; speedup 1.0000x reference)
//
#include <hip/hip_runtime.h>

#define MROWS 16384
#define KD 2048
#define NQ 256
#define NE 64
#define INV_SQRT_DQ 0.0625f
#define NOISE_STD_C 0.1f

typedef _Float16 f16x8 __attribute__((ext_vector_type(8)));
typedef float f32x4 __attribute__((ext_vector_type(4)));
typedef float f32x16 __attribute__((ext_vector_type(16)));

__device__ inline void split8v(f32x4 a, f32x4 b, f16x8* h, f16x8* l) {
    f16x8 hh, ll;
#pragma unroll
    for (int i = 0; i < 4; ++i) {
        _Float16 s = (_Float16)a[i];
        hh[i] = s; ll[i] = (_Float16)(a[i] - (float)s);
    }
#pragma unroll
    for (int i = 0; i < 4; ++i) {
        _Float16 s = (_Float16)b[i];
        hh[4 + i] = s; ll[4 + i] = (_Float16)(b[i] - (float)s);
    }
    *h = hh; *l = ll;
}

// ---------------------------------------------------------------------------
// Kernel 1: w_q [2048][256] f32 -> 32x32x16 B-fragment-packed hi/lo f16.
// Frag (K16, ngrp): lane l holds w[K16*16 + (l>>5)*8 + j][ngrp*32 + (l&31)],
// at linear f16 offset ((K16*8 + ngrp)*64 + l)*8 + j.  65536 octets.
__global__ void prep_w(const float* __restrict__ w, _Float16* __restrict__ whp,
                       _Float16* __restrict__ wlp) {
    const int tid = blockIdx.x * 256 + threadIdx.x;
    const int l = tid & 63;
    const int ngrp = (tid >> 6) & 7;
    const int K16 = tid >> 9;
    const int n = ngrp * 32 + (l & 31);
    const int k = K16 * 16 + (l >> 5) * 8;
    f16x8 h, lo;
#pragma unroll
    for (int j = 0; j < 8; ++j) {
        float v = w[(size_t)(k + j) * NQ + n];
        _Float16 s = (_Float16)v;
        h[j] = s;
        lo[j] = (_Float16)(v - (float)s);
    }
    *(f16x8*)(whp + (size_t)tid * 8) = h;
    *(f16x8*)(wlp + (size_t)tid * 8) = lo;
}

// ---------------------------------------------------------------------------
// Kernel 2 (fused): query GEMM (3-pass f16-split, 32x32x16 MFMA, 2-way K-split)
// + logits + top-2 + softmax + scatter. BM=64, BN=256. grid 256, 512 threads:
// wave wv: g=wv>>2 (k-half), w=wv&3 (64-col n-slice). Ping-pong LDS per group,
// one lgkm-only barrier per iter; B frag-packed in L2, 2-phase reg pipeline.
__global__ __launch_bounds__(512, 2) void gemm_fused(
    const float* __restrict__ x, const _Float16* __restrict__ whp,
    const _Float16* __restrict__ wlp, const float* __restrict__ bq,
    const float* __restrict__ keys, const float* __restrict__ noise,
    float* __restrict__ gate, float* __restrict__ idxout) {
    // LDS map (bytes): [0,65536) A tiles: group g at g*32768, ping-pong tile
    // (Ah 8KB + Al 8KB) at +cb*16384.  Epilogue: qs f32[64][260] (66560 B)
    // aliases A from 0; LG f32[64][65] (16640 B) at 66560. Total 83200.
    __shared__ __align__(16) char smem[83200];

    const int t = threadIdx.x;
    const int lane = t & 63;
    const int wv = t >> 6;
    const int g = wv >> 2;            // k-half: k in [g*1024, g*1024+1024)
    const int w = wv & 3;             // n-slice [w*64, w*64+64)
    const int m0 = blockIdx.x * 64;

    // ---- staging identity: thread stages 16 f32 of its own group's tile
    const int g2 = t >> 8;            // == g (waves 0-3 stage tile 0, 4-7 tile 1)
    const int tt = t & 255;
    const int srow = tt & 63;
    const int opair = tt >> 6;        // octet pair {0,1},{2,3},{4,5},{6,7}
    const float* xs = x + (size_t)(m0 + srow) * KD + g2 * 1024 + opair * 16;
    const int sw0 = ((opair * 2 + 0) ^ (srow & 7)) * 8;  // XOR-swizzled octets
    const int sw1 = ((opair * 2 + 1) ^ (srow & 7)) * 8;
    const int srowoff = srow * 64;
    _Float16* SgBase = (_Float16*)smem + g2 * 16384;     // f16 units

    // ---- B pointers (frag-packed): elem off = K16*4096 + ngrp*512 + lane*8
    const _Float16* bph = whp + (size_t)g * 262144 + w * 1024 + lane * 8;
    const _Float16* bpl = wlp + (size_t)g * 262144 + w * 1024 + lane * 8;

    f32x16 acc[2][2];
#pragma unroll
    for (int mt = 0; mt < 2; ++mt)
#pragma unroll
        for (int nt = 0; nt < 2; ++nt)
#pragma unroll
            for (int r = 0; r < 16; ++r) acc[mt][nt][r] = 0.f;

    f16x8 Bh[2][2], Bl[2][2];  // [slot][nt], slot = phase&1, lookahead 2

#define BLOAD(slot, off) { \
    Bh[slot][0] = *(const f16x8*)(bph + (off)); \
    Bh[slot][1] = *(const f16x8*)(bph + (off) + 512); \
    Bl[slot][0] = *(const f16x8*)(bpl + (off)); \
    Bl[slot][1] = *(const f16x8*)(bpl + (off) + 512); }

#define AREAD(T, ks, mt, ah, al) { \
    int row_ = (mt) * 32 + (lane & 31); \
    int so_ = ((((ks) * 2 + (lane >> 5))) ^ (row_ & 7)) * 8; \
    ah = *(const f16x8*)((T) + row_ * 64 + so_); \
    al = *(const f16x8*)((T) + 4096 + row_ * 64 + so_); }

#define KSTEP(T, ks, slot) { \
    f16x8 a0h, a0l, a1h, a1l; \
    AREAD(T, ks, 0, a0h, a0l); \
    AREAD(T, ks, 1, a1h, a1l); \
    _Pragma("unroll") \
    for (int nt = 0; nt < 2; ++nt) { \
        acc[0][nt] = __builtin_amdgcn_mfma_f32_32x32x16_f16(a0h, Bh[slot][nt], acc[0][nt], 0, 0, 0); \
        acc[0][nt] = __builtin_amdgcn_mfma_f32_32x32x16_f16(a0h, Bl[slot][nt], acc[0][nt], 0, 0, 0); \
        acc[0][nt] = __builtin_amdgcn_mfma_f32_32x32x16_f16(a0l, Bh[slot][nt], acc[0][nt], 0, 0, 0); \
        acc[1][nt] = __builtin_amdgcn_mfma_f32_32x32x16_f16(a1h, Bh[slot][nt], acc[1][nt], 0, 0, 0); \
        acc[1][nt] = __builtin_amdgcn_mfma_f32_32x32x16_f16(a1h, Bl[slot][nt], acc[1][nt], 0, 0, 0); \
        acc[1][nt] = __builtin_amdgcn_mfma_f32_32x32x16_f16(a1l, Bh[slot][nt], acc[1][nt], 0, 0, 0); \
    } }

    // ---- prologue: tile 0 staged, B phases 0,1 loaded, tile 1 prefetched
    f32x4 x0 = __builtin_nontemporal_load((const f32x4*)xs);
    f32x4 x1 = __builtin_nontemporal_load((const f32x4*)(xs + 4));
    f32x4 x2 = __builtin_nontemporal_load((const f32x4*)(xs + 8));
    f32x4 x3 = __builtin_nontemporal_load((const f32x4*)(xs + 12));
    BLOAD(0, 0);
    BLOAD(1, 4096);
    {
        f16x8 h8, l8;
        split8v(x0, x1, &h8, &l8);
        *(f16x8*)(SgBase + srowoff + sw0) = h8;
        *(f16x8*)(SgBase + 4096 + srowoff + sw0) = l8;
        split8v(x2, x3, &h8, &l8);
        *(f16x8*)(SgBase + srowoff + sw1) = h8;
        *(f16x8*)(SgBase + 4096 + srowoff + sw1) = l8;
    }
    x0 = __builtin_nontemporal_load((const f32x4*)(xs + 64));
    x1 = __builtin_nontemporal_load((const f32x4*)(xs + 68));
    x2 = __builtin_nontemporal_load((const f32x4*)(xs + 72));
    x3 = __builtin_nontemporal_load((const f32x4*)(xs + 76));
    __syncthreads();  // one-time full drain

    // ---- K loop: 16 iters of BK=64 per k-group (phases p = 4i+ks, B at p+2)
#pragma unroll 2
    for (int i = 0; i < 16; ++i) {
        const int cb = i & 1;
        const _Float16* T = (const _Float16*)smem + g * 16384 + cb * 8192;
        const size_t ib = (size_t)i * 16384;

        KSTEP(T, 0, 0);
        BLOAD(0, ib + 8192);                       // phase 4i+2 -> slot0
        if (i < 15) {                              // stage tile i+1
            f16x8 h8, l8;
            _Float16* Sn = SgBase + (cb ^ 1) * 8192;
            split8v(x0, x1, &h8, &l8);
            *(f16x8*)(Sn + srowoff + sw0) = h8;
            *(f16x8*)(Sn + 4096 + srowoff + sw0) = l8;
            split8v(x2, x3, &h8, &l8);
            *(f16x8*)(Sn + srowoff + sw1) = h8;
            *(f16x8*)(Sn + 4096 + srowoff + sw1) = l8;
        }
        if (i < 14) {                              // x prefetch tile i+2
            x0 = __builtin_nontemporal_load((const f32x4*)(xs + (i + 2) * 64));
            x1 = __builtin_nontemporal_load((const f32x4*)(xs + (i + 2) * 64 + 4));
            x2 = __builtin_nontemporal_load((const f32x4*)(xs + (i + 2) * 64 + 8));
            x3 = __builtin_nontemporal_load((const f32x4*)(xs + (i + 2) * 64 + 12));
        }
        KSTEP(T, 1, 1);
        BLOAD(1, ib + 12288);                      // phase 4i+3 -> slot1
        KSTEP(T, 2, 0);
        if (i < 15) BLOAD(0, ib + 16384);          // phase 4(i+1) -> slot0
        KSTEP(T, 3, 1);
        if (i < 15) BLOAD(1, ib + 20480);          // phase 4(i+1)+1 -> slot1
        // lgkm-only barrier: publish LDS writes, keep vm prefetches in flight
        __builtin_amdgcn_s_waitcnt(0xC07F);
        __builtin_amdgcn_s_barrier();
    }
    __syncthreads();  // all LDS reads done before qs aliases A buffers

    // ---- epilogue: combine k-groups, +bias, park q in LDS
    // C/D 32x32 layout: col=lane&31, row=(reg&3)+8*(reg>>2)+4*(lane>>5)
    float* qs = (float*)smem;  // [64][260]
    if (g == 0) {
#pragma unroll
        for (int nt = 0; nt < 2; ++nt) {
            int col = w * 64 + nt * 32 + (lane & 31);
            float bias = bq[col];
#pragma unroll
            for (int mt = 0; mt < 2; ++mt)
#pragma unroll
                for (int r = 0; r < 16; ++r) {
                    int row = mt * 32 + (r & 3) + 8 * (r >> 2) + 4 * (lane >> 5);
                    qs[row * 260 + col] = acc[mt][nt][r] + bias;
                }
        }
    }
    __syncthreads();
    if (g == 1) {
#pragma unroll
        for (int nt = 0; nt < 2; ++nt) {
            int col = w * 64 + nt * 32 + (lane & 31);
#pragma unroll
            for (int mt = 0; mt < 2; ++mt)
#pragma unroll
                for (int r = 0; r < 16; ++r) {
                    int row = mt * 32 + (r & 3) + 8 * (r >> 2) + 4 * (lane >> 5);
                    qs[row * 260 + col] += acc[mt][nt][r];
                }
        }
    }
    __syncthreads();

    // ---- logits: waves 0..3, wave = 16-expert slice, 16x16x32 MFMA from LDS q
    const int f = lane & 15;
    const int qq = lane >> 4;
    const int e = (wv & 3) * 16 + f;
    float* LG = (float*)(smem + 66560);  // [64][65], disjoint from qs
    if (wv < 4) {
        f32x4 a2[4];
#pragma unroll
        for (int mt = 0; mt < 4; ++mt) a2[mt] = {0.f, 0.f, 0.f, 0.f};
        const float* kp = keys + (size_t)e * NQ + qq * 8;
        for (int kc = 0; kc < NQ; kc += 32) {
            f32x4 b0 = *(const f32x4*)(kp + kc);
            f32x4 b1 = *(const f32x4*)(kp + kc + 4);
            f16x8 bh2, bl2;
            split8v(b0, b1, &bh2, &bl2);
#pragma unroll
            for (int mt = 0; mt < 4; ++mt) {
                const float* ap = qs + (mt * 16 + f) * 260 + kc + qq * 8;
                f32x4 a0 = *(const f32x4*)ap;
                f32x4 a1 = *(const f32x4*)(ap + 4);
                f16x8 ah2, al2;
                split8v(a0, a1, &ah2, &al2);
                a2[mt] = __builtin_amdgcn_mfma_f32_16x16x32_f16(ah2, bh2, a2[mt], 0, 0, 0);
                a2[mt] = __builtin_amdgcn_mfma_f32_16x16x32_f16(ah2, bl2, a2[mt], 0, 0, 0);
                a2[mt] = __builtin_amdgcn_mfma_f32_16x16x32_f16(al2, bh2, a2[mt], 0, 0, 0);
            }
        }
#pragma unroll
        for (int mt = 0; mt < 4; ++mt)
#pragma unroll
            for (int r = 0; r < 4; ++r) {
                int row = mt * 16 + qq * 4 + r;
                LG[row * 65 + e] = a2[mt][r] * INV_SQRT_DQ +
                                   NOISE_STD_C * noise[(size_t)(m0 + row) * NE + e];
            }
    }
    __syncthreads();

    // ---- top-2 + softmax + scatter: 8 waves x 8 rows, lane = expert
    for (int i = 0; i < 8; ++i) {
        int r = wv * 8 + i;
        float v = LG[r * 65 + lane];
        float v1 = v; int i1 = lane;
#pragma unroll
        for (int off = 32; off; off >>= 1) {
            float ov = __shfl_xor(v1, off);
            int oi = __shfl_xor(i1, off);
            if (ov > v1 || (ov == v1 && oi < i1)) { v1 = ov; i1 = oi; }
        }
        float v2 = (lane == i1) ? -1e30f : v;
        int i2 = lane;
#pragma unroll
        for (int off = 32; off; off >>= 1) {
            float ov = __shfl_xor(v2, off);
            int oi = __shfl_xor(i2, off);
            if (ov > v2 || (ov == v2 && oi < i2)) { v2 = ov; i2 = oi; }
        }
        float ex = expf(v2 - v1);           // v2 <= v1, stable
        float p1 = 1.0f / (1.0f + ex);
        float p2 = ex * p1;
        float gpr = (lane == i1) ? p1 : ((lane == i2) ? p2 : 0.0f);
        gate[(size_t)(m0 + r) * NE + lane] = gpr;
        if (lane == 0) {
            float2 ii = make_float2((float)i1, (float)i2);
            *(float2*)(idxout + (size_t)(m0 + r) * 2) = ii;
        }
    }
}

// ---------------------------------------------------------------------------
extern "C" void kernel_launch(void* const* d_in, const int* in_sizes, int n_in,
                              void* d_out, int out_size, void* d_ws, size_t ws_size,
                              hipStream_t stream) {
    const float* x     = (const float*)d_in[0];
    const float* noise = (const float*)d_in[1];
    const float* w_q   = (const float*)d_in[2];
    const float* b_q   = (const float*)d_in[3];
    const float* keys  = (const float*)d_in[4];
    float* out = (float*)d_out;

    char* ws = (char*)d_ws;
    _Float16* whp = (_Float16*)ws;                 // 1 MB, 32x32-frag-packed hi
    _Float16* wlp = (_Float16*)(ws + (1u << 20));  // 1 MB, 32x32-frag-packed lo

    prep_w<<<256, 256, 0, stream>>>(w_q, whp, wlp);
    gemm_fused<<<256, 512, 0, stream>>>(x, whp, wlp, b_q, keys, noise,
                                        out, out + (size_t)MROWS * NE);
}

// Round 6
// 247.309 us; speedup vs baseline: 1.1209x; 1.1209x over previous
//
#include <hip/hip_runtime.h>

#define MROWS 16384
#define KD 2048
#define NQ 256
#define NE 64
#define INV_SQRT_DQ 0.0625f
#define NOISE_STD_C 0.1f

typedef _Float16 f16x8 __attribute__((ext_vector_type(8)));
typedef _Float16 f16x4 __attribute__((ext_vector_type(4)));
typedef float f32x4 __attribute__((ext_vector_type(4)));

__device__ inline void split8v(f32x4 a, f32x4 b, f16x8* h, f16x8* l) {
    f16x8 hh, ll;
#pragma unroll
    for (int i = 0; i < 4; ++i) {
        _Float16 s = (_Float16)a[i];
        hh[i] = s; ll[i] = (_Float16)(a[i] - (float)s);
    }
#pragma unroll
    for (int i = 0; i < 4; ++i) {
        _Float16 s = (_Float16)b[i];
        hh[4 + i] = s; ll[4 + i] = (_Float16)(b[i] - (float)s);
    }
    *h = hh; *l = ll;
}

__device__ inline void split4v(f32x4 a, f16x4* h, f16x4* l) {
    f16x4 hh, ll;
#pragma unroll
    for (int i = 0; i < 4; ++i) {
        _Float16 s = (_Float16)a[i];
        hh[i] = s; ll[i] = (_Float16)(a[i] - (float)s);
    }
    *h = hh; *l = ll;
}

// ---------------------------------------------------------------------------
// Kernel 1 (unchanged, validated): w_q [2048][256] f32 -> 16x16x32
// B-fragment-packed hi/lo f16.  K32-chunk stride 8192 f16, ngrp stride 512.
__global__ void prep_w(const float* __restrict__ w, _Float16* __restrict__ whp,
                       _Float16* __restrict__ wlp) {
    const int tid = blockIdx.x * 256 + threadIdx.x;
    const int f    = tid & 15;
    const int q    = (tid >> 4) & 3;
    const int ngrp = (tid >> 6) & 15;
    const int kcs  = tid >> 10;
    const int n = ngrp * 16 + f;
    const int k = kcs * 32 + q * 8;
    f16x8 h, l;
#pragma unroll
    for (int j = 0; j < 8; ++j) {
        float v = w[(size_t)(k + j) * NQ + n];
        _Float16 s = (_Float16)v;
        h[j] = s;
        l[j] = (_Float16)(v - (float)s);
    }
    *(f16x8*)(whp + (size_t)tid * 8) = h;
    *(f16x8*)(wlp + (size_t)tid * 8) = l;
}

// ---------------------------------------------------------------------------
// Kernel 2 (fused): query GEMM (3-pass f16-split, 16x16x32 MFMA) + logits +
// top-2 + softmax + scatter.  BM=32, BN=256, BK=64, 32 iters, ping-pong LDS,
// K-loop shape copied from the R3-validated kernel (B next-iter register
// double-buffer, fenced lgkm-only barrier).  grid 512, 512 threads -> 2
// blocks/CU (LDS 41.6 KB, launch_bounds(512,4)): sibling block hides barrier
// stalls that lock-stepped the 1-block/CU versions.
__global__ __launch_bounds__(512, 4) void gemm_fused(
    const float* __restrict__ x, const _Float16* __restrict__ whp,
    const _Float16* __restrict__ wlp, const float* __restrict__ bq,
    const float* __restrict__ keys, const float* __restrict__ noise,
    float* __restrict__ gate, float* __restrict__ idxout) {
    // LDS (bytes): ping-pong A [0,16384): buf cb at cb*8192 = Ah[32][64] f16
    // (4KB) + Al (4KB).  Epilogue overlay: qs f32[32][260] (33280 B) from 0;
    // LG f32[32][65] (8320 B) at 33280.  Total 41600.
    __shared__ __align__(16) char smem[41600];

    const int t = threadIdx.x;
    const int lane = t & 63;
    const int wv = t >> 6;              // 0..7, n-slice [32*wv, 32*wv+32)
    const int m0 = blockIdx.x * 32;
    const int f = lane & 15;
    const int qq = lane >> 4;           // 0..3

    // ---- staging: thread stages 4 f32: row srow, k [kq4, kq4+4)
    const int srow = t >> 4;            // 0..31
    const int kq4 = (t & 15) * 4;       // 0,4,...,60
    const float* xs = x + (size_t)(m0 + srow) * KD + kq4;
    // XOR-octet swizzle (matches read side: octet o at col (o ^ (row&7))*8)
    const int scol = (((kq4 >> 3) ^ (srow & 7)) * 8) + (kq4 & 7);
    const int sa = srow * 64 + scol;    // f16 units within Ah; Al at +2048

    // ---- B pointers (frag-packed; layout independent of BM)
    const _Float16* bph = whp + (size_t)(2 * wv) * 512 + lane * 8;
    const _Float16* bpl = wlp + (size_t)(2 * wv) * 512 + lane * 8;

    f32x4 acc[2][2];
#pragma unroll
    for (int mt = 0; mt < 2; ++mt)
#pragma unroll
        for (int nt = 0; nt < 2; ++nt) acc[mt][nt] = {0.f, 0.f, 0.f, 0.f};

    f16x8 bhC[2][2], blC[2][2], bhN[2][2], blN[2][2];

#define BLOADN(i) { \
    size_t base_ = (size_t)(2 * (i)) * 8192; \
    _Pragma("unroll") \
    for (int ks = 0; ks < 2; ++ks) \
        _Pragma("unroll") \
        for (int nt = 0; nt < 2; ++nt) { \
            size_t o_ = base_ + (size_t)ks * 8192 + nt * 512; \
            bhN[ks][nt] = *(const f16x8*)(bph + o_); \
            blN[ks][nt] = *(const f16x8*)(bpl + o_); \
        } }

#define STAGE(dstf16, xv) { \
    f16x4 h4, l4; \
    split4v(xv, &h4, &l4); \
    *(f16x4*)((dstf16) + sa) = h4; \
    *(f16x4*)((dstf16) + 2048 + sa) = l4; }

#define KSTEP(T, ks) { \
    f16x8 ah[2], al[2]; \
    _Pragma("unroll") \
    for (int mt = 0; mt < 2; ++mt) { \
        int ab = (mt * 16 + f) * 64 + ((((ks) * 4 + qq) ^ (f & 7)) * 8); \
        ah[mt] = *(const f16x8*)((T) + ab); \
        al[mt] = *(const f16x8*)((T) + 2048 + ab); \
    } \
    _Pragma("unroll") \
    for (int mt = 0; mt < 2; ++mt) \
        _Pragma("unroll") \
        for (int nt = 0; nt < 2; ++nt) { \
            acc[mt][nt] = __builtin_amdgcn_mfma_f32_16x16x32_f16(ah[mt], bhC[ks][nt], acc[mt][nt], 0, 0, 0); \
            acc[mt][nt] = __builtin_amdgcn_mfma_f32_16x16x32_f16(ah[mt], blC[ks][nt], acc[mt][nt], 0, 0, 0); \
            acc[mt][nt] = __builtin_amdgcn_mfma_f32_16x16x32_f16(al[mt], bhC[ks][nt], acc[mt][nt], 0, 0, 0); \
        } }

    // ---- prologue (R3 shape): x tile0, B(0) into current regs, stage tile0,
    // prefetch x tile1, one full-drain barrier.
    f32x4 xr = __builtin_nontemporal_load((const f32x4*)xs);
#pragma unroll
    for (int ks = 0; ks < 2; ++ks)
#pragma unroll
        for (int nt = 0; nt < 2; ++nt) {
            size_t o = (size_t)ks * 8192 + nt * 512;
            bhC[ks][nt] = *(const f16x8*)(bph + o);
            blC[ks][nt] = *(const f16x8*)(bpl + o);
        }
    STAGE((_Float16*)smem, xr);
    xr = __builtin_nontemporal_load((const f32x4*)(xs + 64));
    __syncthreads();  // one-time full drain

    // ---- K loop: 32 iters of BK=64 (exact R3 ordering)
    for (int i = 0; i < 32; ++i) {
        const int cb = i & 1;
        const _Float16* T = (const _Float16*)smem + cb * 4096;
        _Float16* Sn = (_Float16*)smem + (cb ^ 1) * 4096;

        if (i + 1 < 32) BLOADN(i + 1);          // next-iter B into bhN/blN
        if (i + 1 < 32) STAGE(Sn, xr);          // stage tile i+1 (xr from i-1)
        if (i + 2 < 32)                         // prefetch x tile i+2
            xr = __builtin_nontemporal_load((const f32x4*)(xs + (i + 2) * 64));
        KSTEP(T, 0);
        KSTEP(T, 1);
#pragma unroll
        for (int ks = 0; ks < 2; ++ks)
#pragma unroll
            for (int nt = 0; nt < 2; ++nt) {
                bhC[ks][nt] = bhN[ks][nt];
                blC[ks][nt] = blN[ks][nt];
            }
        // fenced lgkm-only barrier (validated R3 idiom): publish LDS writes,
        // keep B/x prefetches in flight across the barrier.
        asm volatile("" ::: "memory");
        __builtin_amdgcn_s_waitcnt(0xC07F);  // lgkmcnt(0) only
        __builtin_amdgcn_s_barrier();
        asm volatile("" ::: "memory");
    }
    __syncthreads();  // drain everything before qs aliases the A buffers

    // ---- epilogue: +bias, park q tile (f32) in LDS
    float* qs = (float*)smem;  // [32][260]
#pragma unroll
    for (int nt = 0; nt < 2; ++nt) {
        int col = wv * 32 + nt * 16 + f;
        float bias = bq[col];
#pragma unroll
        for (int mt = 0; mt < 2; ++mt)
#pragma unroll
            for (int r = 0; r < 4; ++r)
                qs[(mt * 16 + qq * 4 + r) * 260 + col] = acc[mt][nt][r] + bias;
    }
    __syncthreads();

    // ---- logits: 8 waves = (row-half rh = wv>>2) x (16-expert slice wv&3)
    const int e = (wv & 3) * 16 + f;
    const int rh = wv >> 2;              // rows [rh*16, rh*16+16)
    float* LG = (float*)(smem + 33280);  // [32][65], disjoint from qs
    {
        f32x4 a2 = {0.f, 0.f, 0.f, 0.f};
        const float* kp = keys + (size_t)e * NQ + qq * 8;
        for (int kc = 0; kc < NQ; kc += 32) {
            f32x4 b0 = *(const f32x4*)(kp + kc);
            f32x4 b1 = *(const f32x4*)(kp + kc + 4);
            f16x8 bh2, bl2;
            split8v(b0, b1, &bh2, &bl2);
            const float* ap = qs + (rh * 16 + f) * 260 + kc + qq * 8;
            f32x4 a0 = *(const f32x4*)ap;
            f32x4 a1 = *(const f32x4*)(ap + 4);
            f16x8 ah2, al2;
            split8v(a0, a1, &ah2, &al2);
            a2 = __builtin_amdgcn_mfma_f32_16x16x32_f16(ah2, bh2, a2, 0, 0, 0);
            a2 = __builtin_amdgcn_mfma_f32_16x16x32_f16(ah2, bl2, a2, 0, 0, 0);
            a2 = __builtin_amdgcn_mfma_f32_16x16x32_f16(al2, bh2, a2, 0, 0, 0);
        }
#pragma unroll
        for (int r = 0; r < 4; ++r) {
            int row = rh * 16 + qq * 4 + r;
            LG[row * 65 + e] = a2[r] * INV_SQRT_DQ +
                               NOISE_STD_C * noise[(size_t)(m0 + row) * NE + e];
        }
    }
    __syncthreads();

    // ---- top-2 + softmax + scatter: 8 waves x 4 rows, lane = expert
    for (int i = 0; i < 4; ++i) {
        int r = wv * 4 + i;
        float v = LG[r * 65 + lane];
        float v1 = v; int i1 = lane;
#pragma unroll
        for (int off = 32; off; off >>= 1) {
            float ov = __shfl_xor(v1, off);
            int oi = __shfl_xor(i1, off);
            if (ov > v1 || (ov == v1 && oi < i1)) { v1 = ov; i1 = oi; }
        }
        float v2 = (lane == i1) ? -1e30f : v;
        int i2 = lane;
#pragma unroll
        for (int off = 32; off; off >>= 1) {
            float ov = __shfl_xor(v2, off);
            int oi = __shfl_xor(i2, off);
            if (ov > v2 || (ov == v2 && oi < i2)) { v2 = ov; i2 = oi; }
        }
        float ex = expf(v2 - v1);           // v2 <= v1, stable
        float p1 = 1.0f / (1.0f + ex);
        float p2 = ex * p1;
        float g = (lane == i1) ? p1 : ((lane == i2) ? p2 : 0.0f);
        gate[(size_t)(m0 + r) * NE + lane] = g;
        if (lane == 0) {
            float2 ii = make_float2((float)i1, (float)i2);
            *(float2*)(idxout + (size_t)(m0 + r) * 2) = ii;
        }
    }
}

// ---------------------------------------------------------------------------
extern "C" void kernel_launch(void* const* d_in, const int* in_sizes, int n_in,
                              void* d_out, int out_size, void* d_ws, size_t ws_size,
                              hipStream_t stream) {
    const float* x     = (const float*)d_in[0];
    const float* noise = (const float*)d_in[1];
    const float* w_q   = (const float*)d_in[2];
    const float* b_q   = (const float*)d_in[3];
    const float* keys  = (const float*)d_in[4];
    float* out = (float*)d_out;

    char* ws = (char*)d_ws;
    _Float16* whp = (_Float16*)ws;                 // 1 MB, frag-packed hi
    _Float16* wlp = (_Float16*)(ws + (1u << 20));  // 1 MB, frag-packed lo

    prep_w<<<256, 256, 0, stream>>>(w_q, whp, wlp);
    gemm_fused<<<512, 512, 0, stream>>>(x, whp, wlp, b_q, keys, noise,
                                        out, out + (size_t)MROWS * NE);
}